// Round 9
// baseline (90.630 us; speedup 1.0000x reference)
//
#include <hip/hip_runtime.h>
#include <math.h>

// ---------------------------------------------------------------------------
// FullyQuantumRNN, round 9: two-kernel split.
// R8 post-mortem: single fused kernel = 41us, killed by (a) per-block
// redundant eval+contract (~3k instr + 6 barriers x 512 blocks), (b) 558k LDS
// bank conflicts from uniform ds_read_b128 A-rows, (c) 2 blocks/CU occupancy.
// R9: qrnn_setup (1 block; R8-verbatim eval + R6-VALIDATED direct contraction
// -> A[18][28] in d_ws) + qrnn_run (512 blocks; A via same-address global
// loads = L1/scalar broadcast, no LDS; LDS trimmed to 48.6KB -> 3 blocks/CU).
// Phase2 recurrence + readout: R8 verbatim (R6-validated).
// ---------------------------------------------------------------------------

typedef __attribute__((ext_vector_type(2))) float f2;

// ---- compile-time permutation algebra (R1..R6-verified) ----
constexpr int cnot_ct(int idx, int c, int t) {
    return (idx & (1 << (4 - c))) ? (idx ^ (1 << (4 - t))) : idx;
}
constexpr int Pfwd_ct(int x, int r) {
    for (int w = 4; w >= 0; --w) x = cnot_ct(x, w, (w + r) % 5);
    return x;
}
constexpr int Pinv_ct(int x, int r) {
    for (int w = 0; w <= 4; ++w) x = cnot_ct(x, w, (w + r) % 5);
    return x;
}
static_assert(Pinv_ct(Pfwd_ct(13, 1), 1) == 13, "inv1");
static_assert(Pinv_ct(Pfwd_ct(22, 2), 2) == 22, "inv2");

constexpr int GMASK[10] = {16, 8, 4, 2, 1,
                           Pfwd_ct(16,1), Pfwd_ct(8,1), Pfwd_ct(4,1), Pfwd_ct(2,1), Pfwd_ct(1,1)};
constexpr int fmask_l1(int pb) {
    int f = 0;
    for (int b = 0; b < 5; ++b) if ((Pinv_ct(1 << b, 1) >> pb) & 1) f |= 1 << b;
    return f;
}
constexpr int FMASK[10] = {16, 8, 4, 2, 1,
                           fmask_l1(4), fmask_l1(3), fmask_l1(2), fmask_l1(1), fmask_l1(0)};
constexpr int cinv_ct(int x) { return Pinv_ct(Pinv_ct(x, 1), 2); }
constexpr int fmask_fin(int pb) {
    int f = 0;
    for (int b = 0; b < 5; ++b) if ((cinv_ct(1 << b) >> pb) & 1) f |= 1 << b;
    return f;
}
constexpr int SF3 = fmask_fin(1);
constexpr int SF4 = fmask_fin(0);
constexpr int FMf(int b) { return Pfwd_ct(Pfwd_ct(1 << b, 2), 1); }

constexpr unsigned span3_ct(int a, int b, int c) {
    unsigned m = 0;
    for (int i = 0; i < 8; ++i) {
        int v = ((i & 1) ? a : 0) ^ ((i & 2) ? b : 0) ^ ((i & 4) ? c : 0);
        m |= 1u << v;
    }
    return m;
}
constexpr unsigned PSPAN = span3_ct(FMf(4), FMf(3), FMf(2));
static_assert(PSPAN == span3_ct(16, 1, 14), "p-stage basis {16,1,14} spans PSPAN");
constexpr bool in_pspan(int v) { return (PSPAN >> (v & 31)) & 1; }
constexpr bool pspan_ok() {
    for (int v = 0; v < 32; ++v) if ((PSPAN >> v) & 1) {
        if (__builtin_popcount(v & SF3) & 1) return false;
        if (__builtin_popcount(v & SF4) & 1) return false;
    }
    return true;
}
static_assert(pspan_ok(), "sign functionals vanish on PSPAN");
static_assert((SF3 & 16) == 0 && (SF4 & 16) == 0, "signs lane-only");

constexpr int QM1 = 12;
constexpr int QM0 = 8;
static_assert((QM1 & 16) == 0 && (QM0 & 16) == 0, "q reps lane-only");
static_assert(in_pspan(QM1 ^ FMf(1)), "QM1 ~ FMf(1) mod PSPAN");
static_assert(in_pspan(QM0 ^ FMf(0)), "QM0 ~ FMf(0) mod PSPAN");
static_assert(!in_pspan(QM1) && !in_pspan(QM0) && !in_pspan(QM1 ^ QM0),
              "q reps independent mod duplication subgroup");
static_assert(span3_ct(1, 2, 7) == 0xFFu, "butterfly {1,2,7} spans lanes 0..7");

// ---- lane relabel A (R5..R8): A(1)=15, A(2)=7, A(4)=2, A(8)=1 ----
constexpr int A4(int l) {
    return ((l & 1) ? 15 : 0) ^ ((l & 2) ? 7 : 0) ^ ((l & 4) ? 2 : 0) ^ ((l & 8) ? 1 : 0);
}
constexpr int Ainv4(int p) {
    for (int l = 0; l < 16; ++l) if (A4(l) == p) return l;
    return -1;
}
constexpr bool a_bij() {
    for (int p = 0; p < 16; ++p) { int l = Ainv4(p); if (l < 0 || A4(l) != p) return false; }
    for (int p = 0; p < 16; ++p) {
        int lin = ((p&1)?Ainv4(1):0) ^ ((p&2)?Ainv4(2):0) ^ ((p&4)?Ainv4(4):0) ^ ((p&8)?Ainv4(8):0);
        if (lin != Ainv4(p)) return false;
    }
    return true;
}
static_assert(a_bij(), "A bijective, inverse linear");

__device__ __forceinline__ int ainv_rt(int p) {
    return ((p & 1) ? Ainv4(1) : 0) ^ ((p & 2) ? Ainv4(2) : 0) ^
           ((p & 4) ? Ainv4(4) : 0) ^ ((p & 8) ? Ainv4(8) : 0);
}
__device__ __forceinline__ int pinv_rt(int x, int r) {
    #pragma unroll
    for (int w = 0; w < 5; ++w) {
        int cbit = 1 << (4 - w), tbit = 1 << (4 - ((w + r) % 5));
        if (x & cbit) x ^= tbit;
    }
    return x;
}

// ---- cross-lane xor move via DPP ----
template<int CTRL> __device__ __forceinline__ float dppf(float x) {
    return __int_as_float(__builtin_amdgcn_mov_dpp(__float_as_int(x), CTRL, 0xF, 0xF, true));
}
template<int PL> __device__ __forceinline__ float mvf(float x) {
    if constexpr (PL == 0)  return x;
    else if constexpr (PL == 1)  return dppf<0xB1>(x);    // quad_perm xor1
    else if constexpr (PL == 2)  return dppf<0x4E>(x);    // quad_perm xor2
    else if constexpr (PL == 3)  return dppf<0x1B>(x);    // quad_perm xor3
    else if constexpr (PL == 7)  return dppf<0x141>(x);   // row_half_mirror = xor7
    else if constexpr (PL == 8)  return dppf<0x128>(x);   // row_ror:8 = xor8
    else if constexpr (PL == 15) return dppf<0x140>(x);   // row_mirror = xor15
    else if constexpr (PL & 8)   return mvf<PL ^ 15>(dppf<0x140>(x));
    else                         return mvf<PL ^ 7>(dppf<0x141>(x));
}

// ---- one Ry gate (R5..R8 verbatim) ----
template<int g>
__device__ __forceinline__ void ry_gate(f2& VR, f2& VI,
                                        const f2 (&C2)[10], const f2 (&S2)[10]) {
    constexpr int m  = GMASK[g];
    constexpr int rm = (m >> 4) & 1;
    constexpr int pl = A4(m & 15);
    f2 PR, PI;
    if constexpr (rm == 0) {
        PR.x = mvf<pl>(VR.x); PR.y = mvf<pl>(VR.y);
        PI.x = mvf<pl>(VI.x); PI.y = mvf<pl>(VI.y);
    } else {
        PR.x = mvf<pl>(VR.y); PR.y = mvf<pl>(VR.x);
        PI.x = mvf<pl>(VI.y); PI.y = mvf<pl>(VI.x);
    }
    VR = C2[g] * VR + S2[g] * PR;
    VI = C2[g] * VI + S2[g] * PI;
}

// ===========================================================================
// kernel 1: ONE block. Eval 243 combos (R8-verbatim loop) -> Q in LDS,
// then R6-VALIDATED direct contraction -> A_g[18][28] in d_ws.
// ===========================================================================
__global__ __launch_bounds__(256) void qrnn_setup(
    const float* __restrict__ w_rec, float* __restrict__ A_g) {

    __shared__ float Qs[488];

    const int tloc = threadIdx.x;
    const int grp  = tloc >> 4;
    const int k    = tloc & 15;

    {
        const int l = ainv_rt(k);
        f2 C2[10], S2[10];
        #pragma unroll
        for (int gg = 0; gg < 10; ++gg) {
            const float the = w_rec[(gg / 5) * 15 + (gg % 5) * 3 + 1];
            const float c = cosf(0.5f * the), s = sinf(0.5f * the);
            const bool bl = __popc(l & (FMASK[gg] & 15)) & 1;
            const bool fb = (FMASK[gg] >> 4) & 1;
            const float sg = bl ? s : -s;
            C2[gg].x = c;  C2[gg].y = c;
            S2[gg].x = sg; S2[gg].y = fb ? -sg : sg;
        }
        f2 P0r2, P0i2, E1r2, E1i2;
        #pragma unroll
        for (int r = 0; r < 2; ++r) {
            const int s_idx = (r << 4) | l;
            const int j     = pinv_rt(s_idx, 1);
            float a0 = 0.f, e1 = 0.f;
            #pragma unroll
            for (int w = 0; w < 5; ++w) {
                const float sg0 = ((s_idx >> (4 - w)) & 1) ? 0.5f : -0.5f;
                const float sg1 = ((j     >> (4 - w)) & 1) ? 0.5f : -0.5f;
                a0 += sg0 * w_rec[w * 3 + 0];
                e1 += sg0 * w_rec[w * 3 + 2];
                e1 += sg1 * w_rec[15 + w * 3 + 0];
            }
            if (r == 0) { P0r2.x = cosf(a0); P0i2.x = sinf(a0);
                          E1r2.x = cosf(e1); E1i2.x = sinf(e1); }
            else        { P0r2.y = cosf(a0); P0i2.y = sinf(a0);
                          E1r2.y = cosf(e1); E1i2.y = sinf(e1); }
        }
        const float s3f = (__popc(l & SF3) & 1) ? -1.f : 1.f;
        const float s4f = (__popc(l & SF4) & 1) ? -1.f : 1.f;
        const float CH[3] = {1.f, 0.5f, 0.5f};
        const float SH[3] = {0.f, 0.86602540378443865f, -0.86602540378443865f};

        #pragma unroll 1
        for (int ci = 0; ci < 16; ++ci) {
            const int combo = grp + (ci << 4);
            if (combo < 243) {
                const int d0 = combo / 81, d1 = (combo / 27) % 3, d2 = (combo / 9) % 3,
                          d3 = (combo / 3) % 3, d4 = combo % 3;
                const float c0  = CH[d0], s0 = SH[d0];
                const float f1  = (l & 8) ? SH[d1] : CH[d1];
                const float f2v = (l & 4) ? SH[d2] : CH[d2];
                const float f3  = (l & 2) ? SH[d3] : CH[d3];
                const float f4  = (l & 1) ? SH[d4] : CH[d4];

                const float Xl = (f1 * f2v) * (f3 * f4);
                f2 bp; bp.x = c0 * Xl; bp.y = s0 * Xl;
                f2 VR = bp * P0r2;
                f2 VI = bp * P0i2;

                ry_gate<0>(VR, VI, C2, S2); ry_gate<1>(VR, VI, C2, S2);
                ry_gate<2>(VR, VI, C2, S2); ry_gate<3>(VR, VI, C2, S2);
                ry_gate<4>(VR, VI, C2, S2);
                {
                    const f2 nr = VR * E1r2 - VI * E1i2;
                    const f2 ni = VR * E1i2 + VI * E1r2;
                    VR = nr; VI = ni;
                }
                ry_gate<5>(VR, VI, C2, S2); ry_gate<6>(VR, VI, C2, S2);
                ry_gate<7>(VR, VI, C2, S2); ry_gate<8>(VR, VI, C2, S2);
                ry_gate<9>(VR, VI, C2, S2);

                const f2 P = VR * VR + VI * VI;
                float tq = P.x + P.y;
                tq += mvf<A4(1)>(tq);
                tq += mvf<A4(14)>(tq);
                float q0 = s3f * tq, q1 = s4f * tq;
                q0 += mvf<A4(QM1)>(q0); q1 += mvf<A4(QM1)>(q1);
                q0 += mvf<A4(QM0)>(q0); q1 += mvf<A4(QM0)>(q1);

                if (k == 0) { Qs[combo * 2 + 0] = q0; Qs[combo * 2 + 1] = q1; }
            }
        }
    }
    __syncthreads();

    // ---- direct contraction (R6-validated numerics), Q from LDS ----
    const float W[3][3] = {{1.f/3.f, 1.f/3.f, 1.f/3.f},
                           {2.f/3.f, -1.f/3.f, -1.f/3.f},
                           {0.f, 0.57735026918962576f, -0.57735026918962576f}};
    for (int o = tloc; o < 486; o += 256) {
        const int row = o / 27, col = o % 27;
        const int j = row / 9, pq = row % 9, p = pq / 3, q = pq % 3;
        const int a0 = col / 9, a1 = (col / 3) % 3, a2 = col % 3;
        float acc = 0.f;
        for (int d0 = 0; d0 < 3; ++d0)
        for (int d1 = 0; d1 < 3; ++d1)
        for (int d2 = 0; d2 < 3; ++d2) {
            const float w012 = W[a0][d0] * W[a1][d1] * W[a2][d2];
            for (int d3 = 0; d3 < 3; ++d3)
            for (int d4 = 0; d4 < 3; ++d4) {
                const int c = (((d0 * 3 + d1) * 3 + d2) * 3 + d3) * 3 + d4;
                acc = fmaf(w012 * W[p][d3] * W[q][d4], Qs[c * 2 + j], acc);
            }
        }
        A_g[row * 28 + col] = acc;        // row stride 28 (16B-aligned rows)
    }
    if (tloc < 18) A_g[tloc * 28 + 27] = 0.f;   // pad col (d_ws is poisoned)
}

// ===========================================================================
// kernel 2: 512 blocks, 3 blocks/CU. A via same-address global loads
// (L1 broadcast, zero LDS conflicts). Phase2 + readout R6/R8-verbatim.
// ===========================================================================
__global__ __launch_bounds__(256, 3) void qrnn_run(
    const float* __restrict__ x_seq, const float* __restrict__ w_out,
    const float* __restrict__ A_g, float* __restrict__ out, int B) {

    __shared__ __align__(16) float4 xs4[16 * 33];   // [local-batch][step], padded
    __shared__ float Cm[16][19][33];                // [batch][row(+zero)][t]

    const int tloc = threadIdx.x;
    const int grp  = tloc >> 4;
    const int k    = tloc & 15;
    const int b0   = blockIdx.x * 16;
    const int b    = b0 + grp;

    // ---- stage x (coalesced global reads; padded LDS rows) ----
    #pragma unroll
    for (int qq = 0; qq < 2; ++qq) {
        const int p = tloc + qq * 256;
        const int ts = p >> 4, lbs = p & 15;
        const int gidx = (ts * B + (b0 + lbs)) * 3;
        float4 v;
        v.x = x_seq[gidx]; v.y = x_seq[gidx + 1]; v.z = x_seq[gidx + 2]; v.w = 0.f;
        xs4[lbs * 33 + ts] = v;
    }
    __syncthreads();

    // ---- phase 1: C[t][row] = A-row . Xb(t); lane (grp,k) -> t = k, k+16 ----
    constexpr float Kf = 0.15915494309189535f;   // 1/(2*pi)
    float Xb0[28], Xb1[28];
    #pragma unroll
    for (int tt = 0; tt < 2; ++tt) {
        float* Xb = tt ? Xb1 : Xb0;
        const float4 xv = xs4[grp * 33 + k + 16 * tt];
        const float cx0 = __builtin_amdgcn_cosf(xv.x * Kf);
        const float sx0 = __builtin_amdgcn_cosf(fmaf(xv.x, Kf, -0.25f));
        const float cx1 = __builtin_amdgcn_cosf(xv.y * Kf);
        const float sx1 = __builtin_amdgcn_cosf(fmaf(xv.y, Kf, -0.25f));
        const float cx2 = __builtin_amdgcn_cosf(xv.z * Kf);
        const float sx2 = __builtin_amdgcn_cosf(fmaf(xv.z, Kf, -0.25f));
        Xb[0] = 1.f;  Xb[1] = cx2;       Xb[2] = sx2;
        Xb[3] = cx1;  Xb[4] = cx1 * cx2; Xb[5] = cx1 * sx2;
        Xb[6] = sx1;  Xb[7] = sx1 * cx2; Xb[8] = sx1 * sx2;
        #pragma unroll
        for (int i = 0; i < 9; ++i) { Xb[9 + i] = cx0 * Xb[i]; Xb[18 + i] = sx0 * Xb[i]; }
        Xb[27] = 0.f;
    }
    {
        const float4* A4p = (const float4*)A_g;     // wave-uniform addresses
        #pragma unroll 1
        for (int r = 0; r < 18; ++r) {
            float4 av[7];
            #pragma unroll
            for (int i = 0; i < 7; ++i) av[i] = A4p[r * 7 + i];
            float a00 = 0.f, a01 = 0.f, a10 = 0.f, a11 = 0.f;
            #pragma unroll
            for (int i = 0; i < 7; ++i) {
                a00 = fmaf(av[i].x, Xb0[4*i+0], a00); a00 = fmaf(av[i].y, Xb0[4*i+1], a00);
                a01 = fmaf(av[i].z, Xb0[4*i+2], a01); a01 = fmaf(av[i].w, Xb0[4*i+3], a01);
                a10 = fmaf(av[i].x, Xb1[4*i+0], a10); a10 = fmaf(av[i].y, Xb1[4*i+1], a10);
                a11 = fmaf(av[i].z, Xb1[4*i+2], a11); a11 = fmaf(av[i].w, Xb1[4*i+3], a11);
            }
            Cm[grp][r][k]      = a00 + a01;
            Cm[grp][r][k + 16] = a10 + a11;
        }
        Cm[grp][18][k] = 0.f; Cm[grp][18][k + 16] = 0.f;
    }
    // C written/read within the same wave (16-lane group) -> no barrier

    // ---- phase 2: recurrence; lane k = coefficient slot (R6/R8 verbatim) ----
    const int jj = k >> 3;
    const int term = (k & 7) + 1;
    const int rowA = jj * 9 + term;
    const int rowB = (k == 0) ? 0 : ((k == 8) ? 9 : 18);
    const int p = term / 3, q = term % 3;
    const float* CA_ptr = &Cm[grp][rowA][0];
    const float* CB_ptr = &Cm[grp][rowB][0];

    float h0 = 0.f, h1 = 0.f;
    float CA = CA_ptr[0], CB = CB_ptr[0];
    #pragma unroll 1
    for (int t = 0; t < 32; ++t) {
        const int tn = (t < 31) ? t + 1 : 31;
        const float CAn = CA_ptr[tn], CBn = CB_ptr[tn];
        const float ch0 = __builtin_amdgcn_cosf(h0 * Kf);
        const float sh0 = __builtin_amdgcn_cosf(fmaf(h0, Kf, -0.25f));
        const float ch1 = __builtin_amdgcn_cosf(h1 * Kf);
        const float sh1 = __builtin_amdgcn_cosf(fmaf(h1, Kf, -0.25f));
        const float u = (p == 1) ? ch0 : ((p == 2) ? sh0 : 1.f);
        const float v = (q == 1) ? ch1 : ((q == 2) ? sh1 : 1.f);
        float val = fmaf(CA, u * v, CB);
        val += mvf<1>(val);
        val += mvf<2>(val);
        val += mvf<7>(val);
        const float other = mvf<8>(val);
        h0 = (k & 8) ? other : val;
        h1 = (k & 8) ? val : other;
        CA = CAn; CB = CBn;
    }

    // ---- readout: 2-qubit circuit (R1/R5/R6-verified), libm trig ----
    const float sh0 = sinf(0.5f * h0), ch0 = cosf(0.5f * h0);
    const float sh1 = sinf(0.5f * h1), ch1 = cosf(0.5f * h1);
    float vr0 = ch0 * ch1, vr1 = ch0 * sh1, vr2 = sh0 * ch1, vr3 = sh0 * sh1;
    float vi0 = 0.f, vi1 = 0.f, vi2 = 0.f, vi3 = 0.f;

    #pragma unroll
    for (int li = 0; li < 2; ++li) {
        #pragma unroll
        for (int w = 0; w < 2; ++w) {
            const float phi = w_out[li * 6 + w * 3 + 0];
            const float the = w_out[li * 6 + w * 3 + 1];
            const float ome = w_out[li * 6 + w * 3 + 2];
            const float cs = cosf(0.5f * the), ss = sinf(0.5f * the);
            const float cp = cosf(0.5f * (phi + ome)), sp = sinf(0.5f * (phi + ome));
            const float cm = cosf(0.5f * (phi - ome)), sm = sinf(0.5f * (phi - ome));
            const float are = cp * cs, aim = -sp * cs;
            const float bre = cm * ss, bim = sm * ss;
            #define AP2(r0, i0, r1, i1) do {                                  \
                float n0r = are*(r0) - aim*(i0) - bre*(r1) + bim*(i1);        \
                float n0i = are*(i0) + aim*(r0) - bre*(i1) - bim*(r1);        \
                float n1r = bre*(r0) + bim*(i0) + are*(r1) + aim*(i1);        \
                float n1i = bre*(i0) - bim*(r0) + are*(i1) - aim*(r1);        \
                r0 = n0r; i0 = n0i; r1 = n1r; i1 = n1i; } while (0)
            if (w == 0) { AP2(vr0, vi0, vr2, vi2); AP2(vr1, vi1, vr3, vi3); }
            else        { AP2(vr0, vi0, vr1, vi1); AP2(vr2, vi2, vr3, vi3); }
            #undef AP2
        }
        float tr1 = vr2, ti1 = vi2, tr2 = vr3, ti2 = vi3, tr3 = vr1, ti3 = vi1;
        vr1 = tr1; vi1 = ti1; vr2 = tr2; vi2 = ti2; vr3 = tr3; vi3 = ti3;
    }

    const float outv = (vr0 * vr0 + vi0 * vi0 + vr1 * vr1 + vi1 * vi1) -
                       (vr2 * vr2 + vi2 * vi2 + vr3 * vr3 + vi3 * vi3);
    if (k == 0) out[b] = outv;
}

extern "C" void kernel_launch(void* const* d_in, const int* in_sizes, int n_in,
                              void* d_out, int out_size, void* d_ws, size_t ws_size,
                              hipStream_t stream) {
    const float* x_seq = (const float*)d_in[0];
    const float* w_rec = (const float*)d_in[1];
    const float* w_out = (const float*)d_in[2];
    float* out = (float*)d_out;
    float* A_g = (float*)d_ws;          // 18*28 floats

    const int B = out_size;             // 8192 (T fixed at 32 by the bench)
    const int grid = (B * 16) / 256;    // 512 blocks

    hipLaunchKernelGGL(qrnn_setup, dim3(1), dim3(256), 0, stream, w_rec, A_g);
    hipLaunchKernelGGL(qrnn_run, dim3(grid), dim3(256), 0, stream,
                       x_seq, w_out, A_g, out, B);
}

// Round 10
// 77.879 us; speedup vs baseline: 1.1637x; 1.1637x over previous
//
#include <hip/hip_runtime.h>
#include <math.h>

// ---------------------------------------------------------------------------
// FullyQuantumRNN, round 10: two kernels, setup made PARALLEL.
// R9 post-mortem: qrnn_setup (1 block) was latency-bound: ~70 serial libm
// calls/thread + 243-term serial contraction at 1 wave/SIMD ~ 20-30us.
// R10 setup: (a) all libm trig distributed one-call-per-thread -> LDS (depth
// ~2); (b) each of 243 threads simulates the full 32-amp circuit in registers
// for its combo (zero cross-lane, R4-verified conventions: new[i]=old[P(i)],
// E1 = w0(i)+phi1(Pinv(i,1)), expZ sign bits); (c) R6-validated contraction
// -> A[18][28] + 16 readout coefs in d_ws.
// R10 run: R9 verbatim except readout uses precomputed w_out coefs + HW trig
// for h (HW h-trig validated R4/R5 at 2.4e-7) -- cuts ~1.6k instr/thread.
// ---------------------------------------------------------------------------

typedef __attribute__((ext_vector_type(2))) float f2;

// ---- compile-time permutation algebra (R1..R6-verified) ----
constexpr int cnot_ct(int idx, int c, int t) {
    return (idx & (1 << (4 - c))) ? (idx ^ (1 << (4 - t))) : idx;
}
constexpr int Pfwd_ct(int x, int r) {            // new[i] = old[Pfwd(i)]
    for (int w = 4; w >= 0; --w) x = cnot_ct(x, w, (w + r) % 5);
    return x;
}
constexpr int Pinv_ct(int x, int r) {
    for (int w = 0; w <= 4; ++w) x = cnot_ct(x, w, (w + r) % 5);
    return x;
}
static_assert(Pinv_ct(Pfwd_ct(13, 1), 1) == 13, "inv1");
static_assert(Pinv_ct(Pfwd_ct(22, 2), 2) == 22, "inv2");

struct PermT { int v[32]; };
constexpr PermT mkperm(int r) {
    PermT p{};
    for (int i = 0; i < 32; ++i) p.v[i] = Pfwd_ct(i, r);
    return p;
}
constexpr PermT PT1 = mkperm(1);
constexpr PermT PT2 = mkperm(2);

__device__ __forceinline__ int pinv_rt(int x, int r) {
    #pragma unroll
    for (int w = 0; w < 5; ++w) {
        int cbit = 1 << (4 - w), tbit = 1 << (4 - ((w + r) % 5));
        if (x & cbit) x ^= tbit;
    }
    return x;
}

// ---- cross-lane xor move via DPP (used by run-kernel recurrence only) ----
template<int CTRL> __device__ __forceinline__ float dppf(float x) {
    return __int_as_float(__builtin_amdgcn_mov_dpp(__float_as_int(x), CTRL, 0xF, 0xF, true));
}
template<int PL> __device__ __forceinline__ float mvf(float x) {
    if constexpr (PL == 0)  return x;
    else if constexpr (PL == 1)  return dppf<0xB1>(x);    // quad_perm xor1
    else if constexpr (PL == 2)  return dppf<0x4E>(x);    // quad_perm xor2
    else if constexpr (PL == 7)  return dppf<0x141>(x);   // row_half_mirror = xor7
    else if constexpr (PL == 8)  return dppf<0x128>(x);   // row_ror:8 = xor8
    else { static_assert(PL == 0 || PL == 1 || PL == 2 || PL == 7 || PL == 8, "mask"); return x; }
}

// ---- full-state Ry on wire with pair-mask M: [[c,-s],[s,c]] ----
template<int M>
__device__ __forceinline__ void ry_full(float (&ar)[32], float (&ai)[32],
                                        float c, float s) {
    #pragma unroll
    for (int i = 0; i < 32; ++i) {
        if (!(i & M)) {
            const int j = i | M;
            const float a0r = ar[i], a0i = ai[i], a1r = ar[j], a1i = ai[j];
            ar[i] = c * a0r - s * a1r;  ai[i] = c * a0i - s * a1i;
            ar[j] = s * a0r + c * a1r;  ai[j] = s * a0i + c * a1i;
        }
    }
}

// ===========================================================================
// kernel 1 (1 block): parallel trig -> per-thread full-state eval (243
// combos) -> R6-validated contraction -> d_ws: A[18][28] + RC[16]
// ===========================================================================
__global__ __launch_bounds__(256, 1) void qrnn_setup(
    const float* __restrict__ w_rec, const float* __restrict__ w_out,
    float* __restrict__ ws) {

    __shared__ float CgS[10], SgS[10];          // cos/sin(theta_g/2)
    __shared__ float P0c[32], P0s[32];          // D_phi0 phase per amp
    __shared__ float E1c[32], E1s[32];          // merged D_w0 * P1-frame D_phi1
    __shared__ float RC[16];                    // readout coefs
    __shared__ float Qs[488];

    const int tid = threadIdx.x;

    // ---- stage A: all libm trig, one value per thread (depth ~1-3 calls) ----
    if (tid < 10) {                             // Ry coefs
        const float th = w_rec[(tid / 5) * 15 + (tid % 5) * 3 + 1];
        CgS[tid] = cosf(0.5f * th);
        SgS[tid] = sinf(0.5f * th);
    } else if (tid >= 32 && tid < 96) {         // per-amp phases
        const int idx = tid - 32;
        const int i = idx & 31;
        float ang = 0.f;
        if (idx < 32) {                         // a0(i) = sum +-phi0_w/2
            #pragma unroll
            for (int w = 0; w < 5; ++w)
                ang += (((i >> (4 - w)) & 1) ? 0.5f : -0.5f) * w_rec[w * 3 + 0];
            P0c[i] = cosf(ang); P0s[i] = sinf(ang);
        } else {                                // e1(i) = +-w0_w/2 + +-phi1_w/2 @ Pinv
            const int j = pinv_rt(i, 1);
            #pragma unroll
            for (int w = 0; w < 5; ++w) {
                ang += (((i >> (4 - w)) & 1) ? 0.5f : -0.5f) * w_rec[w * 3 + 2];
                ang += (((j >> (4 - w)) & 1) ? 0.5f : -0.5f) * w_rec[15 + w * 3 + 0];
            }
            E1c[i] = cosf(ang); E1s[i] = sinf(ang);
        }
    } else if (tid >= 96 && tid < 100) {        // readout gate coefs
        const int g = tid - 96;                 // g = li*2 + w
        const int li = g >> 1, w = g & 1;
        const float phi = w_out[li * 6 + w * 3 + 0];
        const float the = w_out[li * 6 + w * 3 + 1];
        const float ome = w_out[li * 6 + w * 3 + 2];
        const float cs = cosf(0.5f * the), ss = sinf(0.5f * the);
        const float cp = cosf(0.5f * (phi + ome)), sp = sinf(0.5f * (phi + ome));
        const float cm = cosf(0.5f * (phi - ome)), sm = sinf(0.5f * (phi - ome));
        RC[g * 4 + 0] = cp * cs;    // are
        RC[g * 4 + 1] = -sp * cs;   // aim
        RC[g * 4 + 2] = cm * ss;    // bre
        RC[g * 4 + 3] = sm * ss;    // bim
    }
    __syncthreads();

    // ---- stage B: per-thread full-state eval at exact combo angles ----
    if (tid < 243) {
        const int d0 = tid / 81, d1 = (tid / 27) % 3, d2 = (tid / 9) % 3,
                  d3 = (tid / 3) % 3, d4 = tid % 3;
        const float C3[3] = {1.f, 0.5f, 0.5f};
        const float S3[3] = {0.f, 0.86602540378443865f, -0.86602540378443865f};
        const float f0c = C3[d0], f0s = S3[d0], f1c = C3[d1], f1s = S3[d1],
                    f2c = C3[d2], f2s = S3[d2], f3c = C3[d3], f3s = S3[d3],
                    f4c = C3[d4], f4s = S3[d4];

        float ar[32], ai[32];
        #pragma unroll
        for (int i = 0; i < 32; ++i) {          // product state * D_phi0
            const float b = ((i & 16) ? f0s : f0c) * ((i & 8) ? f1s : f1c) *
                            ((i & 4) ? f2s : f2c) * ((i & 2) ? f3s : f3c) *
                            ((i & 1) ? f4s : f4c);
            ar[i] = b * P0c[i]; ai[i] = b * P0s[i];
        }
        // layer 0 Ry's (wires 0..4)
        ry_full<16>(ar, ai, CgS[0], SgS[0]);
        ry_full<8>(ar, ai, CgS[1], SgS[1]);
        ry_full<4>(ar, ai, CgS[2], SgS[2]);
        ry_full<2>(ar, ai, CgS[3], SgS[3]);
        ry_full<1>(ar, ai, CgS[4], SgS[4]);
        // merged diagonal E1 (D_omega1 dropped: phase-blind)
        #pragma unroll
        for (int i = 0; i < 32; ++i) {
            const float nr = ar[i] * E1c[i] - ai[i] * E1s[i];
            const float ni = ar[i] * E1s[i] + ai[i] * E1c[i];
            ar[i] = nr; ai[i] = ni;
        }
        // CNOT ring r=1: new[i] = old[PT1[i]] (compile-time renaming)
        float br[32], bi[32];
        #pragma unroll
        for (int i = 0; i < 32; ++i) { br[i] = ar[PT1.v[i]]; bi[i] = ai[PT1.v[i]]; }
        // layer 1 Ry's
        ry_full<16>(br, bi, CgS[5], SgS[5]);
        ry_full<8>(br, bi, CgS[6], SgS[6]);
        ry_full<4>(br, bi, CgS[7], SgS[7]);
        ry_full<2>(br, bi, CgS[8], SgS[8]);
        ry_full<1>(br, bi, CgS[9], SgS[9]);
        // CNOT ring r=2 + expZ(wire3=bit1, wire4=bit0)
        float q0 = 0.f, q1 = 0.f;
        #pragma unroll
        for (int i = 0; i < 32; ++i) {
            const int src = PT2.v[i];
            const float p = br[src] * br[src] + bi[src] * bi[src];
            q0 += ((i >> 1) & 1) ? -p : p;
            q1 += (i & 1) ? -p : p;
        }
        Qs[tid * 2 + 0] = q0; Qs[tid * 2 + 1] = q1;
    }
    __syncthreads();

    // ---- stage C: direct contraction (R6-validated numerics) ----
    const float W[3][3] = {{1.f/3.f, 1.f/3.f, 1.f/3.f},
                           {2.f/3.f, -1.f/3.f, -1.f/3.f},
                           {0.f, 0.57735026918962576f, -0.57735026918962576f}};
    for (int o = tid; o < 486; o += 256) {
        const int row = o / 27, col = o % 27;
        const int j = row / 9, pq = row % 9, p = pq / 3, q = pq % 3;
        const int a0 = col / 9, a1 = (col / 3) % 3, a2 = col % 3;
        float acc = 0.f;
        for (int dd0 = 0; dd0 < 3; ++dd0)
        for (int dd1 = 0; dd1 < 3; ++dd1)
        for (int dd2 = 0; dd2 < 3; ++dd2) {
            const float w012 = W[a0][dd0] * W[a1][dd1] * W[a2][dd2];
            for (int dd3 = 0; dd3 < 3; ++dd3)
            for (int dd4 = 0; dd4 < 3; ++dd4) {
                const int c = (((dd0 * 3 + dd1) * 3 + dd2) * 3 + dd3) * 3 + dd4;
                acc = fmaf(w012 * W[p][dd3] * W[q][dd4], Qs[c * 2 + j], acc);
            }
        }
        ws[row * 28 + col] = acc;
    }
    if (tid < 18) ws[tid * 28 + 27] = 0.f;      // pad col (d_ws is poisoned)
    if (tid < 16) ws[18 * 28 + tid] = RC[tid];  // readout coefs
}

// ===========================================================================
// kernel 2 (512 blocks, 3/CU): phase1 C=A.Xb, phase2 recurrence, readout.
// R9 verbatim except readout (precomputed coefs + HW h-trig).
// ===========================================================================
__global__ __launch_bounds__(256, 3) void qrnn_run(
    const float* __restrict__ x_seq, const float* __restrict__ A_g,
    float* __restrict__ out, int B) {

    __shared__ __align__(16) float4 xs4[16 * 33];   // [local-batch][step], padded
    __shared__ float Cm[16][19][33];                // [batch][row(+zero)][t]

    const int tloc = threadIdx.x;
    const int grp  = tloc >> 4;
    const int k    = tloc & 15;
    const int b0   = blockIdx.x * 16;
    const int b    = b0 + grp;

    // ---- stage x (coalesced; padded LDS rows) ----
    #pragma unroll
    for (int qq = 0; qq < 2; ++qq) {
        const int p = tloc + qq * 256;
        const int ts = p >> 4, lbs = p & 15;
        const int gidx = (ts * B + (b0 + lbs)) * 3;
        float4 v;
        v.x = x_seq[gidx]; v.y = x_seq[gidx + 1]; v.z = x_seq[gidx + 2]; v.w = 0.f;
        xs4[lbs * 33 + ts] = v;
    }
    __syncthreads();

    // ---- phase 1: C[t][row] = A-row . Xb(t); lane (grp,k) -> t = k, k+16 ----
    constexpr float Kf = 0.15915494309189535f;   // 1/(2*pi)
    float Xb0[28], Xb1[28];
    #pragma unroll
    for (int tt = 0; tt < 2; ++tt) {
        float* Xb = tt ? Xb1 : Xb0;
        const float4 xv = xs4[grp * 33 + k + 16 * tt];
        const float cx0 = __builtin_amdgcn_cosf(xv.x * Kf);
        const float sx0 = __builtin_amdgcn_cosf(fmaf(xv.x, Kf, -0.25f));
        const float cx1 = __builtin_amdgcn_cosf(xv.y * Kf);
        const float sx1 = __builtin_amdgcn_cosf(fmaf(xv.y, Kf, -0.25f));
        const float cx2 = __builtin_amdgcn_cosf(xv.z * Kf);
        const float sx2 = __builtin_amdgcn_cosf(fmaf(xv.z, Kf, -0.25f));
        Xb[0] = 1.f;  Xb[1] = cx2;       Xb[2] = sx2;
        Xb[3] = cx1;  Xb[4] = cx1 * cx2; Xb[5] = cx1 * sx2;
        Xb[6] = sx1;  Xb[7] = sx1 * cx2; Xb[8] = sx1 * sx2;
        #pragma unroll
        for (int i = 0; i < 9; ++i) { Xb[9 + i] = cx0 * Xb[i]; Xb[18 + i] = sx0 * Xb[i]; }
        Xb[27] = 0.f;
    }
    {
        const float4* A4p = (const float4*)A_g;     // wave-uniform addresses
        #pragma unroll 1
        for (int r = 0; r < 18; ++r) {
            float4 av[7];
            #pragma unroll
            for (int i = 0; i < 7; ++i) av[i] = A4p[r * 7 + i];
            float a00 = 0.f, a01 = 0.f, a10 = 0.f, a11 = 0.f;
            #pragma unroll
            for (int i = 0; i < 7; ++i) {
                a00 = fmaf(av[i].x, Xb0[4*i+0], a00); a00 = fmaf(av[i].y, Xb0[4*i+1], a00);
                a01 = fmaf(av[i].z, Xb0[4*i+2], a01); a01 = fmaf(av[i].w, Xb0[4*i+3], a01);
                a10 = fmaf(av[i].x, Xb1[4*i+0], a10); a10 = fmaf(av[i].y, Xb1[4*i+1], a10);
                a11 = fmaf(av[i].z, Xb1[4*i+2], a11); a11 = fmaf(av[i].w, Xb1[4*i+3], a11);
            }
            Cm[grp][r][k]      = a00 + a01;
            Cm[grp][r][k + 16] = a10 + a11;
        }
        Cm[grp][18][k] = 0.f; Cm[grp][18][k + 16] = 0.f;
    }
    // C written/read within the same wave (16-lane group) -> no barrier

    // ---- phase 2: recurrence; lane k = coefficient slot (R6/R9 verbatim) ----
    const int jj = k >> 3;
    const int term = (k & 7) + 1;
    const int rowA = jj * 9 + term;
    const int rowB = (k == 0) ? 0 : ((k == 8) ? 9 : 18);
    const int p = term / 3, q = term % 3;
    const float* CA_ptr = &Cm[grp][rowA][0];
    const float* CB_ptr = &Cm[grp][rowB][0];

    float h0 = 0.f, h1 = 0.f;
    float CA = CA_ptr[0], CB = CB_ptr[0];
    #pragma unroll 1
    for (int t = 0; t < 32; ++t) {
        const int tn = (t < 31) ? t + 1 : 31;
        const float CAn = CA_ptr[tn], CBn = CB_ptr[tn];
        const float ch0 = __builtin_amdgcn_cosf(h0 * Kf);
        const float sh0 = __builtin_amdgcn_cosf(fmaf(h0, Kf, -0.25f));
        const float ch1 = __builtin_amdgcn_cosf(h1 * Kf);
        const float sh1 = __builtin_amdgcn_cosf(fmaf(h1, Kf, -0.25f));
        const float u = (p == 1) ? ch0 : ((p == 2) ? sh0 : 1.f);
        const float v = (q == 1) ? ch1 : ((q == 2) ? sh1 : 1.f);
        float val = fmaf(CA, u * v, CB);
        val += mvf<1>(val);
        val += mvf<2>(val);
        val += mvf<7>(val);
        const float other = mvf<8>(val);
        h0 = (k & 8) ? other : val;
        h1 = (k & 8) ? val : other;
        CA = CAn; CB = CBn;
    }

    // ---- readout: precomputed w_out coefs + HW h-trig (R4/R5-validated) ----
    float rc[16];
    {
        const float4* RCp = (const float4*)(A_g + 18 * 28);
        #pragma unroll
        for (int i = 0; i < 4; ++i) {
            const float4 v = RCp[i];
            rc[4*i+0] = v.x; rc[4*i+1] = v.y; rc[4*i+2] = v.z; rc[4*i+3] = v.w;
        }
    }
    constexpr float K2 = 0.5f * 0.15915494309189535f;    // 0.5/(2*pi)
    const float ch0 = __builtin_amdgcn_cosf(h0 * K2);
    const float sh0 = __builtin_amdgcn_cosf(fmaf(h0, K2, -0.25f));
    const float ch1 = __builtin_amdgcn_cosf(h1 * K2);
    const float sh1 = __builtin_amdgcn_cosf(fmaf(h1, K2, -0.25f));
    float vr0 = ch0 * ch1, vr1 = ch0 * sh1, vr2 = sh0 * ch1, vr3 = sh0 * sh1;
    float vi0 = 0.f, vi1 = 0.f, vi2 = 0.f, vi3 = 0.f;

    #pragma unroll
    for (int li = 0; li < 2; ++li) {
        #pragma unroll
        for (int w = 0; w < 2; ++w) {
            const int g = li * 2 + w;
            const float are = rc[g*4+0], aim = rc[g*4+1];
            const float bre = rc[g*4+2], bim = rc[g*4+3];
            #define AP2(r0, i0, r1, i1) do {                                  \
                float n0r = are*(r0) - aim*(i0) - bre*(r1) + bim*(i1);        \
                float n0i = are*(i0) + aim*(r0) - bre*(i1) - bim*(r1);        \
                float n1r = bre*(r0) + bim*(i0) + are*(r1) + aim*(i1);        \
                float n1i = bre*(i0) - bim*(r0) + are*(i1) - aim*(r1);        \
                r0 = n0r; i0 = n0i; r1 = n1r; i1 = n1i; } while (0)
            if (w == 0) { AP2(vr0, vi0, vr2, vi2); AP2(vr1, vi1, vr3, vi3); }
            else        { AP2(vr0, vi0, vr1, vi1); AP2(vr2, vi2, vr3, vi3); }
            #undef AP2
        }
        // CNOT(0,1) then CNOT(1,0): composed perm [0,2,3,1] (R1-verified)
        float tr1 = vr2, ti1 = vi2, tr2 = vr3, ti2 = vi3, tr3 = vr1, ti3 = vi1;
        vr1 = tr1; vi1 = ti1; vr2 = tr2; vi2 = ti2; vr3 = tr3; vi3 = ti3;
    }

    const float outv = (vr0 * vr0 + vi0 * vi0 + vr1 * vr1 + vi1 * vi1) -
                       (vr2 * vr2 + vi2 * vi2 + vr3 * vr3 + vi3 * vi3);
    if (k == 0) out[b] = outv;
}

extern "C" void kernel_launch(void* const* d_in, const int* in_sizes, int n_in,
                              void* d_out, int out_size, void* d_ws, size_t ws_size,
                              hipStream_t stream) {
    const float* x_seq = (const float*)d_in[0];
    const float* w_rec = (const float*)d_in[1];
    const float* w_out = (const float*)d_in[2];
    float* out = (float*)d_out;
    float* ws  = (float*)d_ws;          // A[18*28] + RC[16]

    const int B = out_size;             // 8192 (T fixed at 32 by the bench)
    const int grid = (B * 16) / 256;    // 512 blocks

    hipLaunchKernelGGL(qrnn_setup, dim3(1), dim3(256), 0, stream, w_rec, w_out, ws);
    hipLaunchKernelGGL(qrnn_run, dim3(grid), dim3(256), 0, stream,
                       x_seq, ws, out, B);
}

// Round 11
// 76.311 us; speedup vs baseline: 1.1876x; 1.0205x over previous
//
#include <hip/hip_runtime.h>
#include <math.h>

// ---------------------------------------------------------------------------
// FullyQuantumRNN, round 11: ONE kernel, redundant-but-PARALLEL per-block setup.
// R10 ledger: floor ~46us + ~11-17us per extra kernel node; setup+run are only
// ~8us of real work. So fuse back to one node, but avoid R8's failure modes:
//  - libm trig distributed one-call-per-thread (R10 stage A)   [R8: 3k serial]
//  - eval: one combo per thread, full 32-amp state in regs, STORAGE FRAME
//    throughout via R2-R8-validated functionals (GMASK/FMASK/SF3/SF4), so no
//    permute buffers (64 live floats) and no cross-lane     [R8: serial DPP]
//  - contraction in 2 separable stages (~150 instr/thread)  [R10 direct: 2k]
//  - Qs/P1s aliased into Cm -> LDS 50.1KB -> 3 blocks/CU    [R8: 2/CU]
// Phase1 (A-rows via wave-uniform ds_read_b128 + 1-row prefetch), phase2
// recurrence, readout: R6/R9/R10-validated structure verbatim.
// ---------------------------------------------------------------------------

// ---- compile-time permutation algebra (R1..R10-verified) ----
constexpr int cnot_ct(int idx, int c, int t) {
    return (idx & (1 << (4 - c))) ? (idx ^ (1 << (4 - t))) : idx;
}
constexpr int Pfwd_ct(int x, int r) {            // new[i] = old[Pfwd(i)]
    for (int w = 4; w >= 0; --w) x = cnot_ct(x, w, (w + r) % 5);
    return x;
}
constexpr int Pinv_ct(int x, int r) {
    for (int w = 0; w <= 4; ++w) x = cnot_ct(x, w, (w + r) % 5);
    return x;
}
static_assert(Pinv_ct(Pfwd_ct(13, 1), 1) == 13, "inv1");
static_assert(Pinv_ct(Pfwd_ct(22, 2), 2) == 22, "inv2");

// gate pair masks (storage-frame) and row-select functionals
constexpr int GMASK[10] = {16, 8, 4, 2, 1,
                           Pfwd_ct(16,1), Pfwd_ct(8,1), Pfwd_ct(4,1), Pfwd_ct(2,1), Pfwd_ct(1,1)};
constexpr int fmask_l1(int pb) {
    int f = 0;
    for (int b = 0; b < 5; ++b) if ((Pinv_ct(1 << b, 1) >> pb) & 1) f |= 1 << b;
    return f;
}
constexpr int FMASK[10] = {16, 8, 4, 2, 1,
                           fmask_l1(4), fmask_l1(3), fmask_l1(2), fmask_l1(1), fmask_l1(0)};
// expZ sign functionals on the storage index (final wires 3,4)
constexpr int cinv_ct(int x) { return Pinv_ct(Pinv_ct(x, 1), 2); }
constexpr int fmask_fin(int pb) {
    int f = 0;
    for (int b = 0; b < 5; ++b) if ((cinv_ct(1 << b) >> pb) & 1) f |= 1 << b;
    return f;
}
constexpr int SF3 = fmask_fin(1);
constexpr int SF4 = fmask_fin(0);

// each gate's pair must straddle its row-functional (one beta=0, one beta=1)
constexpr bool gates_straddle() {
    for (int g = 0; g < 10; ++g)
        if (!(__builtin_popcount(GMASK[g] & FMASK[g]) & 1)) return false;
    return true;
}
static_assert(gates_straddle(), "GMASK/FMASK straddle");

// phase-2 butterfly {1,2,7} spans 8-lane halves (R6-validated scheme)
constexpr unsigned span3_ct(int a, int b, int c) {
    unsigned m = 0;
    for (int i = 0; i < 8; ++i) {
        int v = ((i & 1) ? a : 0) ^ ((i & 2) ? b : 0) ^ ((i & 4) ? c : 0);
        m |= 1u << v;
    }
    return m;
}
static_assert(span3_ct(1, 2, 7) == 0xFFu, "butterfly {1,2,7} spans lanes 0..7");

__device__ __forceinline__ int pinv_rt(int x, int r) {
    #pragma unroll
    for (int w = 0; w < 5; ++w) {
        int cbit = 1 << (4 - w), tbit = 1 << (4 - ((w + r) % 5));
        if (x & cbit) x ^= tbit;
    }
    return x;
}

// ---- cross-lane xor via DPP (phase-2 recurrence only; within 16-lane rows) --
template<int CTRL> __device__ __forceinline__ float dppf(float x) {
    return __int_as_float(__builtin_amdgcn_mov_dpp(__float_as_int(x), CTRL, 0xF, 0xF, true));
}
template<int PL> __device__ __forceinline__ float mvf(float x) {
    if constexpr (PL == 1)      return dppf<0xB1>(x);    // quad_perm xor1
    else if constexpr (PL == 2) return dppf<0x4E>(x);    // quad_perm xor2
    else if constexpr (PL == 7) return dppf<0x141>(x);   // row_half_mirror = xor7
    else if constexpr (PL == 8) return dppf<0x128>(x);   // row_ror:8 = xor8
    else { static_assert(PL == 1 || PL == 2 || PL == 7 || PL == 8, "mask"); return x; }
}

// ---- full-state Ry in storage frame: pair mask m, row functional F ----
template<int g>
__device__ __forceinline__ void gate_full(float (&ar)[32], float (&ai)[32],
                                          float c, float s) {
    constexpr int m = GMASK[g], F = FMASK[g];
    #pragma unroll
    for (int i = 0; i < 32; ++i) {
        if ((__builtin_popcount(i & F) & 1) == 0) {   // beta=0 member of pair
            const int j = i ^ m;                      // beta=1 (straddle assert)
            const float r0 = ar[i], i0 = ai[i], r1 = ar[j], i1 = ai[j];
            ar[i] = c * r0 - s * r1;  ai[i] = c * i0 - s * i1;
            ar[j] = s * r0 + c * r1;  ai[j] = s * i0 + c * i1;
        }
    }
}

__global__ __launch_bounds__(256, 3) void qrnn_fused(
    const float* __restrict__ x_seq, const float* __restrict__ w_rec,
    const float* __restrict__ w_out, float* __restrict__ out, int B) {

    __shared__ __align__(16) float4 xs4[16 * 33];     // staged x, padded rows
    __shared__ __align__(16) float A2s[18 * 28];      // contracted A, padded
    __shared__ float CgS[10], SgS[10];                // cos/sin(theta_g/2)
    __shared__ float P0c[32], P0s[32], E1c[32], E1s[32];
    __shared__ float RC[16];                          // readout coefs
    __shared__ __align__(16) float Cm_pool[16 * 19 * 33];   // Cm; aliases Qs/P1s
    float* const Qs  = Cm_pool;                       // [486] eval results
    float* const P1s = Cm_pool + 512;                 // [486] C1 partials

    const int tloc = threadIdx.x;
    const int grp  = tloc >> 4;
    const int k    = tloc & 15;
    const int b0   = blockIdx.x * 16;
    const int b    = b0 + grp;

    // ---- stage x (coalesced; consumed after barriers below) ----
    #pragma unroll
    for (int qq = 0; qq < 2; ++qq) {
        const int p = tloc + qq * 256;
        const int ts = p >> 4, lbs = p & 15;
        const int gidx = (ts * B + (b0 + lbs)) * 3;
        float4 v;
        v.x = x_seq[gidx]; v.y = x_seq[gidx + 1]; v.z = x_seq[gidx + 2]; v.w = 0.f;
        xs4[lbs * 33 + ts] = v;
    }

    // ---- stage A: all libm trig, distributed (depth ~2 calls) ----
    if (tloc < 10) {
        const float th = w_rec[(tloc / 5) * 15 + (tloc % 5) * 3 + 1];
        CgS[tloc] = cosf(0.5f * th);
        SgS[tloc] = sinf(0.5f * th);
    } else if (tloc >= 32 && tloc < 96) {
        const int idx = tloc - 32;
        const int i = idx & 31;
        float ang = 0.f;
        if (idx < 32) {                         // D_phi0 phase per amp
            #pragma unroll
            for (int w = 0; w < 5; ++w)
                ang += (((i >> (4 - w)) & 1) ? 0.5f : -0.5f) * w_rec[w * 3 + 0];
            P0c[i] = cosf(ang); P0s[i] = sinf(ang);
        } else {                                // E1 = D_w0 * P1-frame D_phi1
            const int j = pinv_rt(i, 1);
            #pragma unroll
            for (int w = 0; w < 5; ++w) {
                ang += (((i >> (4 - w)) & 1) ? 0.5f : -0.5f) * w_rec[w * 3 + 2];
                ang += (((j >> (4 - w)) & 1) ? 0.5f : -0.5f) * w_rec[15 + w * 3 + 0];
            }
            E1c[i] = cosf(ang); E1s[i] = sinf(ang);
        }
    } else if (tloc >= 96 && tloc < 100) {      // readout gate coefs
        const int g = tloc - 96;                // g = li*2 + w
        const int li = g >> 1, w = g & 1;
        const float phi = w_out[li * 6 + w * 3 + 0];
        const float the = w_out[li * 6 + w * 3 + 1];
        const float ome = w_out[li * 6 + w * 3 + 2];
        const float cs = cosf(0.5f * the), ss = sinf(0.5f * the);
        const float cp = cosf(0.5f * (phi + ome)), sp = sinf(0.5f * (phi + ome));
        const float cm = cosf(0.5f * (phi - ome)), sm = sinf(0.5f * (phi - ome));
        RC[g * 4 + 0] = cp * cs;
        RC[g * 4 + 1] = -sp * cs;
        RC[g * 4 + 2] = cm * ss;
        RC[g * 4 + 3] = sm * ss;
    }
    __syncthreads();

    // ---- stage B: per-thread full-state eval at exact combo angles ----
    if (tloc < 243) {
        const int d0 = tloc / 81, d1 = (tloc / 27) % 3, d2 = (tloc / 9) % 3,
                  d3 = (tloc / 3) % 3, d4 = tloc % 3;
        const float C3[3] = {1.f, 0.5f, 0.5f};
        const float S3[3] = {0.f, 0.86602540378443865f, -0.86602540378443865f};
        const float f0c = C3[d0], f0s = S3[d0], f1c = C3[d1], f1s = S3[d1],
                    f2c = C3[d2], f2s = S3[d2], f3c = C3[d3], f3s = S3[d3],
                    f4c = C3[d4], f4s = S3[d4];

        float ar[32], ai[32];
        #pragma unroll
        for (int i = 0; i < 32; ++i) {          // product state * D_phi0
            const float bb = ((i & 16) ? f0s : f0c) * ((i & 8) ? f1s : f1c) *
                             ((i & 4) ? f2s : f2c) * ((i & 2) ? f3s : f3c) *
                             ((i & 1) ? f4s : f4c);
            ar[i] = bb * P0c[i]; ai[i] = bb * P0s[i];
        }
        // layer 0 (masks e_w, rows by own bit)
        gate_full<0>(ar, ai, CgS[0], SgS[0]);
        gate_full<1>(ar, ai, CgS[1], SgS[1]);
        gate_full<2>(ar, ai, CgS[2], SgS[2]);
        gate_full<3>(ar, ai, CgS[3], SgS[3]);
        gate_full<4>(ar, ai, CgS[4], SgS[4]);
        // merged diagonal E1 (D_omega1 dropped: phase-blind)
        #pragma unroll
        for (int i = 0; i < 32; ++i) {
            const float nr = ar[i] * E1c[i] - ai[i] * E1s[i];
            const float ni = ar[i] * E1s[i] + ai[i] * E1c[i];
            ar[i] = nr; ai[i] = ni;
        }
        // layer 1 in storage frame (GMASK/FMASK functionals, no permute)
        gate_full<5>(ar, ai, CgS[5], SgS[5]);
        gate_full<6>(ar, ai, CgS[6], SgS[6]);
        gate_full<7>(ar, ai, CgS[7], SgS[7]);
        gate_full<8>(ar, ai, CgS[8], SgS[8]);
        gate_full<9>(ar, ai, CgS[9], SgS[9]);
        // expZ via SF3/SF4 sign functionals (R2-R8-validated)
        float q0 = 0.f, q1 = 0.f;
        #pragma unroll
        for (int i = 0; i < 32; ++i) {
            const float p = ar[i] * ar[i] + ai[i] * ai[i];
            q0 += (__builtin_popcount(i & SF3) & 1) ? -p : p;
            q1 += (__builtin_popcount(i & SF4) & 1) ? -p : p;
        }
        Qs[tloc * 2 + 0] = q0; Qs[tloc * 2 + 1] = q1;
    }
    __syncthreads();

    // ---- stage C1: contract d3,d4 (W = V^-1, R6-validated constants) ----
    const float W[3][3] = {{1.f/3.f, 1.f/3.f, 1.f/3.f},
                           {2.f/3.f, -1.f/3.f, -1.f/3.f},
                           {0.f, 0.57735026918962576f, -0.57735026918962576f}};
    for (int o = tloc; o < 486; o += 256) {
        const int j = o & 1, e = o >> 1;
        const int d012 = e / 9, pq = e % 9, p = pq / 3, q = pq % 3;
        float acc = 0.f;
        #pragma unroll
        for (int d3 = 0; d3 < 3; ++d3) {
            const float wp = W[p][d3];
            #pragma unroll
            for (int d4 = 0; d4 < 3; ++d4)
                acc = fmaf(wp * W[q][d4], Qs[(d012 * 9 + d3 * 3 + d4) * 2 + j], acc);
        }
        P1s[(d012 * 9 + pq) * 2 + j] = acc;
    }
    __syncthreads();

    // ---- stage C2: contract d0,d1,d2 -> A2s[row=j*9+pq][col=a0*9+a1*3+a2] ----
    for (int o = tloc; o < 486; o += 256) {
        const int row = o / 27, col = o % 27;
        const int j = row / 9, pq = row % 9;
        const int a0 = col / 9, a1 = (col / 3) % 3, a2 = col % 3;
        float acc = 0.f;
        #pragma unroll
        for (int dd0 = 0; dd0 < 3; ++dd0) {
            const float w0 = W[a0][dd0];
            #pragma unroll
            for (int dd1 = 0; dd1 < 3; ++dd1) {
                const float w01 = w0 * W[a1][dd1];
                #pragma unroll
                for (int dd2 = 0; dd2 < 3; ++dd2)
                    acc = fmaf(w01 * W[a2][dd2],
                               P1s[((dd0 * 9 + dd1 * 3 + dd2) * 9 + pq) * 2 + j], acc);
            }
        }
        A2s[row * 28 + col] = acc;
    }
    if (tloc < 18) A2s[tloc * 28 + 27] = 0.f;
    __syncthreads();   // A2s ready; Qs/P1s dead -> Cm_pool reusable

    // ---- phase 1: C[t][row] = A-row . Xb(t); lane (grp,k) -> t = k, k+16 ----
    constexpr float Kf = 0.15915494309189535f;   // 1/(2*pi)
    float Xb0[28], Xb1[28];
    #pragma unroll
    for (int tt = 0; tt < 2; ++tt) {
        float* Xb = tt ? Xb1 : Xb0;
        const float4 xv = xs4[grp * 33 + k + 16 * tt];
        const float cx0 = __builtin_amdgcn_cosf(xv.x * Kf);
        const float sx0 = __builtin_amdgcn_cosf(fmaf(xv.x, Kf, -0.25f));
        const float cx1 = __builtin_amdgcn_cosf(xv.y * Kf);
        const float sx1 = __builtin_amdgcn_cosf(fmaf(xv.y, Kf, -0.25f));
        const float cx2 = __builtin_amdgcn_cosf(xv.z * Kf);
        const float sx2 = __builtin_amdgcn_cosf(fmaf(xv.z, Kf, -0.25f));
        Xb[0] = 1.f;  Xb[1] = cx2;       Xb[2] = sx2;
        Xb[3] = cx1;  Xb[4] = cx1 * cx2; Xb[5] = cx1 * sx2;
        Xb[6] = sx1;  Xb[7] = sx1 * cx2; Xb[8] = sx1 * sx2;
        #pragma unroll
        for (int i = 0; i < 9; ++i) { Xb[9 + i] = cx0 * Xb[i]; Xb[18 + i] = sx0 * Xb[i]; }
        Xb[27] = 0.f;
    }
    {
        const float4* Ap = (const float4*)A2s;      // wave-uniform LDS reads
        float* const Cmg = Cm_pool + grp * (19 * 33);
        float4 av[7], nv[7];
        #pragma unroll
        for (int i = 0; i < 7; ++i) av[i] = Ap[i];
        #pragma unroll 1
        for (int r = 0; r < 18; ++r) {
            if (r < 17) {                           // prefetch next row
                #pragma unroll
                for (int i = 0; i < 7; ++i) nv[i] = Ap[(r + 1) * 7 + i];
            }
            float a00 = 0.f, a01 = 0.f, a10 = 0.f, a11 = 0.f;
            #pragma unroll
            for (int i = 0; i < 7; ++i) {
                a00 = fmaf(av[i].x, Xb0[4*i+0], a00); a00 = fmaf(av[i].y, Xb0[4*i+1], a00);
                a01 = fmaf(av[i].z, Xb0[4*i+2], a01); a01 = fmaf(av[i].w, Xb0[4*i+3], a01);
                a10 = fmaf(av[i].x, Xb1[4*i+0], a10); a10 = fmaf(av[i].y, Xb1[4*i+1], a10);
                a11 = fmaf(av[i].z, Xb1[4*i+2], a11); a11 = fmaf(av[i].w, Xb1[4*i+3], a11);
            }
            Cmg[r * 33 + k]      = a00 + a01;
            Cmg[r * 33 + k + 16] = a10 + a11;
            #pragma unroll
            for (int i = 0; i < 7; ++i) av[i] = nv[i];
        }
        Cmg[18 * 33 + k] = 0.f; Cmg[18 * 33 + k + 16] = 0.f;
    }
    // Cm written/read within the same 16-lane group -> no barrier (validated)

    // ---- phase 2: recurrence; lane k = coefficient slot (R6/R10 verbatim) ----
    const int jj = k >> 3;
    const int term = (k & 7) + 1;
    const int rowA = jj * 9 + term;
    const int rowB = (k == 0) ? 0 : ((k == 8) ? 9 : 18);
    const int p = term / 3, q = term % 3;
    const float* CA_ptr = Cm_pool + grp * (19 * 33) + rowA * 33;
    const float* CB_ptr = Cm_pool + grp * (19 * 33) + rowB * 33;

    float h0 = 0.f, h1 = 0.f;
    float CA = CA_ptr[0], CB = CB_ptr[0];
    #pragma unroll 1
    for (int t = 0; t < 32; ++t) {
        const int tn = (t < 31) ? t + 1 : 31;
        const float CAn = CA_ptr[tn], CBn = CB_ptr[tn];
        const float ch0 = __builtin_amdgcn_cosf(h0 * Kf);
        const float sh0 = __builtin_amdgcn_cosf(fmaf(h0, Kf, -0.25f));
        const float ch1 = __builtin_amdgcn_cosf(h1 * Kf);
        const float sh1 = __builtin_amdgcn_cosf(fmaf(h1, Kf, -0.25f));
        const float u = (p == 1) ? ch0 : ((p == 2) ? sh0 : 1.f);
        const float v = (q == 1) ? ch1 : ((q == 2) ? sh1 : 1.f);
        float val = fmaf(CA, u * v, CB);
        val += mvf<1>(val);
        val += mvf<2>(val);
        val += mvf<7>(val);
        const float other = mvf<8>(val);
        h0 = (k & 8) ? other : val;
        h1 = (k & 8) ? val : other;
        CA = CAn; CB = CBn;
    }

    // ---- readout: precomputed coefs + HW h-trig (R10-validated) ----
    constexpr float K2 = 0.5f * 0.15915494309189535f;
    const float ch0 = __builtin_amdgcn_cosf(h0 * K2);
    const float sh0 = __builtin_amdgcn_cosf(fmaf(h0, K2, -0.25f));
    const float ch1 = __builtin_amdgcn_cosf(h1 * K2);
    const float sh1 = __builtin_amdgcn_cosf(fmaf(h1, K2, -0.25f));
    float vr0 = ch0 * ch1, vr1 = ch0 * sh1, vr2 = sh0 * ch1, vr3 = sh0 * sh1;
    float vi0 = 0.f, vi1 = 0.f, vi2 = 0.f, vi3 = 0.f;

    #pragma unroll
    for (int li = 0; li < 2; ++li) {
        #pragma unroll
        for (int w = 0; w < 2; ++w) {
            const int g = li * 2 + w;
            const float are = RC[g*4+0], aim = RC[g*4+1];
            const float bre = RC[g*4+2], bim = RC[g*4+3];
            #define AP2(r0, i0, r1, i1) do {                                  \
                float n0r = are*(r0) - aim*(i0) - bre*(r1) + bim*(i1);        \
                float n0i = are*(i0) + aim*(r0) - bre*(i1) - bim*(r1);        \
                float n1r = bre*(r0) + bim*(i0) + are*(r1) + aim*(i1);        \
                float n1i = bre*(i0) - bim*(r0) + are*(i1) - aim*(r1);        \
                r0 = n0r; i0 = n0i; r1 = n1r; i1 = n1i; } while (0)
            if (w == 0) { AP2(vr0, vi0, vr2, vi2); AP2(vr1, vi1, vr3, vi3); }
            else        { AP2(vr0, vi0, vr1, vi1); AP2(vr2, vi2, vr3, vi3); }
            #undef AP2
        }
        // CNOT(0,1) then CNOT(1,0): composed perm [0,2,3,1] (R1-verified)
        float tr1 = vr2, ti1 = vi2, tr2 = vr3, ti2 = vi3, tr3 = vr1, ti3 = vi1;
        vr1 = tr1; vi1 = ti1; vr2 = tr2; vi2 = ti2; vr3 = tr3; vi3 = ti3;
    }

    const float outv = (vr0 * vr0 + vi0 * vi0 + vr1 * vr1 + vi1 * vi1) -
                       (vr2 * vr2 + vi2 * vi2 + vr3 * vr3 + vi3 * vi3);
    if (k == 0) out[b] = outv;
}

extern "C" void kernel_launch(void* const* d_in, const int* in_sizes, int n_in,
                              void* d_out, int out_size, void* d_ws, size_t ws_size,
                              hipStream_t stream) {
    const float* x_seq = (const float*)d_in[0];
    const float* w_rec = (const float*)d_in[1];
    const float* w_out = (const float*)d_in[2];
    float* out = (float*)d_out;

    const int B = out_size;             // 8192 (T fixed at 32 by the bench)
    const int grid = (B * 16) / 256;    // 512 blocks, 3/CU by LDS+launch_bounds

    hipLaunchKernelGGL(qrnn_fused, dim3(grid), dim3(256), 0, stream,
                       x_seq, w_rec, w_out, out, B);
}